// Round 6
// baseline (586.841 us; speedup 1.0000x reference)
//
#include <hip/hip_runtime.h>
#include <hip/hip_bf16.h>
#include <stdint.h>

#define NOUT 11008
#define KIN  4096
#define MTOK 4096
#define PLD  5504            // int32 elements per k-row of pw / 8B-granules per k-octet row of wsB
#define BM 256
#define BN 128
#define BK 32
#define NSTEP (KIN/BK)       // 128
#define NTN (NOUT/BN)        // 86
#define NTM (MTOK/BM)        // 16
#define ACHUNK 16384         // bytes per (mt,t) A chunk: 4 octets x 256 rows x 16B
#define WSA_BYTES ((size_t)NTM * NSTEP * ACHUNK)        // 32 MB
#define WSB_OFF   WSA_BYTES

typedef short bf16x8 __attribute__((ext_vector_type(8)));
typedef float f32x16 __attribute__((ext_vector_type(16)));

typedef __attribute__((address_space(3))) uint8_t lds_u8_t;
typedef __attribute__((address_space(1))) const uint8_t glb_u8_t;

__device__ __forceinline__ uint32_t bfpack(float lo, float hi){
    __hip_bfloat16 a = __float2bfloat16(lo);
    __hip_bfloat16 b = __float2bfloat16(hi);
    uint16_t ua, ub;
    __builtin_memcpy(&ua, &a, 2);
    __builtin_memcpy(&ub, &b, 2);
    return (uint32_t)ua | ((uint32_t)ub << 16);
}

// ---------------- pre-pass A: x fp32 -> bf16 chunks [mt*128+t][q-octet][ml][16B] ----------------
__global__ __launch_bounds__(256)
void prepA(const float* __restrict__ x, uint8_t* __restrict__ wsA)
{
    int gid = blockIdx.x * 256 + threadIdx.x;   // 512 octets x 4096 rows
    int o = gid >> 12;                          // global k-octet 0..511
    int m = gid & 4095;
    const float* xp = x + (size_t)m * KIN + o * 8;
    float4 v0 = *reinterpret_cast<const float4*>(xp);
    float4 v1 = *reinterpret_cast<const float4*>(xp + 4);
    uint4 r;
    r.x = bfpack(v0.x, v0.y); r.y = bfpack(v0.z, v0.w);
    r.z = bfpack(v1.x, v1.y); r.w = bfpack(v1.z, v1.w);
    int mt = m >> 8, ml = m & 255, t = o >> 2, q = o & 3;
    *reinterpret_cast<uint4*>(wsA + (size_t)(mt * NSTEP + t) * ACHUNK + q * 4096 + ml * 16) = r;
}

// ---------------- pre-pass B: int32-inflated nibble-pairs -> compact bytes, k-transposed ----------------
// wsB layout: [koct 0..511][np 0..5503] of 8B: packed bytes for k = koct*8+0..7 at column-pair np.
__global__ __launch_bounds__(128)
void prepB(const int32_t* __restrict__ pw, uint8_t* __restrict__ wsB)
{
    int np   = blockIdx.x * 128 + threadIdx.x;     // 43*128 = 5504
    int koct = blockIdx.y;                         // 0..511
    const int32_t* p = pw + (size_t)koct * 8 * PLD + np;
    uint32_t b[8];
#pragma unroll
    for (int i = 0; i < 8; ++i) b[i] = (uint32_t)p[(size_t)i * PLD] & 0xFFu;
    uint32_t lo = b[0] | (b[1] << 8) | (b[2] << 16) | (b[3] << 24);
    uint32_t hi = b[4] | (b[5] << 8) | (b[6] << 16) | (b[7] << 24);
    *reinterpret_cast<uint2*>(wsB + ((size_t)koct * PLD + np) * 8) = make_uint2(lo, hi);
}

// decode one B fragment: 8 nibbles (one column, 8 consecutive k) -> bf16x8, dequantized
__device__ __forceinline__ bf16x8 decodeFrag(uint2 w, uint32_t sh, float s, float m8s)
{
    uint32_t a = (w.x >> sh) & 0x0f0f0f0fu;
    uint32_t b = (w.y >> sh) & 0x0f0f0f0fu;
    float d0 = fmaf((float)(a & 0xffu),         s, m8s);
    float d1 = fmaf((float)((a >> 8) & 0xffu),  s, m8s);
    float d2 = fmaf((float)((a >> 16) & 0xffu), s, m8s);
    float d3 = fmaf((float)(a >> 24),           s, m8s);
    float d4 = fmaf((float)(b & 0xffu),         s, m8s);
    float d5 = fmaf((float)((b >> 8) & 0xffu),  s, m8s);
    float d6 = fmaf((float)((b >> 16) & 0xffu), s, m8s);
    float d7 = fmaf((float)(b >> 24),           s, m8s);
    uint32_t r[4] = { bfpack(d0, d1), bfpack(d2, d3), bfpack(d4, d5), bfpack(d6, d7) };
    bf16x8 out;
    __builtin_memcpy(&out, r, 16);
    return out;
}

// ---------------- main GEMM ----------------
__global__ __launch_bounds__(256, 2)
void qlin_gemm(const uint8_t* __restrict__ wsA, const uint8_t* __restrict__ wsB,
               const float* __restrict__ sc, const float* __restrict__ bias,
               float* __restrict__ y)
{
    __shared__ __align__(16) uint8_t ldsA[4][ACHUNK];   // 64 KB, A only

    const int tid  = threadIdx.x;
    const int lane = tid & 63;
    const int wid  = tid >> 6;
    const int wr = wid >> 1, wc = wid & 1;   // wave tile 128x64

    // bijective XCD swizzle: 1376 = 8 * 172
    const int lb = (blockIdx.x & 7) * 172 + (blockIdx.x >> 3);
    const int mt = lb / NTN, nt = lb % NTN;
    const int m0 = mt * BM, n0 = nt * BN;

    const int l31 = lane & 31;
    const int lh  = lane >> 5;              // k-octet half within K16
    const uint32_t sh4 = (lane & 1) * 4;    // nibble select by column parity

    // A-frag LDS byte offsets [k16][i]
    int aOff[2][4];
#pragma unroll
    for (int k16 = 0; k16 < 2; ++k16)
#pragma unroll
        for (int i = 0; i < 4; ++i)
            aOff[k16][i] = (k16 * 2 + lh) * 4096 + (wr * 128 + i * 32 + l31) * 16;

    // B columns and per-lane wsB byte offsets
    const int n_0 = n0 + wc * 64 + l31;
    const int n_1 = n_0 + 32;
    const size_t bb0 = ((size_t)lh * PLD + (n_0 >> 1)) * 8;
    const size_t bb1 = ((size_t)lh * PLD + (n_1 >> 1)) * 8;
    const float* scb0 = sc + n_0;
    const float* scb1 = sc + n_1;
    const uint8_t* wsAbase = wsA + (size_t)mt * NSTEP * ACHUNK;

    f32x16 acc[4][2];
#pragma unroll
    for (int i = 0; i < 4; ++i)
#pragma unroll
        for (int j = 0; j < 2; ++j)
#pragma unroll
            for (int r = 0; r < 16; ++r)
                acc[i][j][r] = 0.f;

    uint2   brA[4], brB[4];
    bf16x8  bdA[4], bdB[4];
    float   sA0, sA1, sB0, sB1;

#define ISSUEA(tp, WB) do{ \
    const uint8_t* g_ = wsAbase + (size_t)(tp) * ACHUNK + tid * 16; \
    __builtin_amdgcn_global_load_lds((glb_u8_t*)(g_),         (lds_u8_t*)(&ldsA[WB][tid*16]),         16, 0, 0); \
    __builtin_amdgcn_global_load_lds((glb_u8_t*)(g_ + 4096),  (lds_u8_t*)(&ldsA[WB][tid*16 + 4096]),  16, 0, 0); \
    __builtin_amdgcn_global_load_lds((glb_u8_t*)(g_ + 8192),  (lds_u8_t*)(&ldsA[WB][tid*16 + 8192]),  16, 0, 0); \
    __builtin_amdgcn_global_load_lds((glb_u8_t*)(g_ + 12288), (lds_u8_t*)(&ldsA[WB][tid*16 + 12288]), 16, 0, 0); \
}while(0)

#define LOADB(br, S0, S1, tp) do{ \
    const uint8_t* bp_ = wsB + (size_t)(tp) * ((size_t)4 * PLD * 8); \
    br[0] = *reinterpret_cast<const uint2*>(bp_ + bb0); \
    br[1] = *reinterpret_cast<const uint2*>(bp_ + bb0 + (size_t)2 * PLD * 8); \
    br[2] = *reinterpret_cast<const uint2*>(bp_ + bb1); \
    br[3] = *reinterpret_cast<const uint2*>(bp_ + bb1 + (size_t)2 * PLD * 8); \
    S0 = scb0[(size_t)((tp) >> 2) * NOUT]; \
    S1 = scb1[(size_t)((tp) >> 2) * NOUT]; \
}while(0)

#define DECODE(br, bd, S0, S1) do{ \
    const float m80_ = -8.f * (S0), m81_ = -8.f * (S1); \
    bd[0] = decodeFrag(br[0], sh4, (S0), m80_); \
    bd[1] = decodeFrag(br[1], sh4, (S0), m80_); \
    bd[2] = decodeFrag(br[2], sh4, (S1), m81_); \
    bd[3] = decodeFrag(br[3], sh4, (S1), m81_); \
}while(0)

#define COMPUTE(RB, bd) do{ \
    const uint8_t* La_ = ldsA[RB]; \
    bf16x8 af_[2][4]; \
    _Pragma("unroll") \
    for (int k16 = 0; k16 < 2; ++k16) \
        _Pragma("unroll") \
        for (int i = 0; i < 4; ++i) \
            af_[k16][i] = *reinterpret_cast<const bf16x8*>(La_ + aOff[k16][i]); \
    __builtin_amdgcn_s_setprio(1); \
    _Pragma("unroll") \
    for (int i = 0; i < 4; ++i) \
        _Pragma("unroll") \
        for (int j = 0; j < 2; ++j) \
            _Pragma("unroll") \
            for (int k16 = 0; k16 < 2; ++k16) \
                acc[i][j] = __builtin_amdgcn_mfma_f32_32x32x16_bf16(af_[k16][i], bd[j*2 + k16], acc[i][j], 0, 0, 0); \
    __builtin_amdgcn_s_setprio(0); \
}while(0)

#define KBAR() do{ \
    asm volatile("s_waitcnt vmcnt(10)" ::: "memory"); \
    __builtin_amdgcn_sched_barrier(0); \
    __builtin_amdgcn_s_barrier(); \
    asm volatile("" ::: "memory"); \
}while(0)

#define KSTEP(S, RB, WB, brW, sW0, sW1, brD, bdD, sD0, sD1, bdC) do{ \
    const int t_  = tb + (S); \
    const int tp_ = (t_ + 2 <= NSTEP - 1) ? (t_ + 2) : (NSTEP - 1); \
    ISSUEA(tp_, WB); \
    LOADB(brW, sW0, sW1, tp_); \
    DECODE(brD, bdD, sD0, sD1); \
    COMPUTE(RB, bdC); \
    KBAR(); \
}while(0)

    // ---- prologue: stage tiles 0,1; prefetch B tiles 0,1; decode tile 0 ----
    ISSUEA(0, 0);
    ISSUEA(1, 1);
    {
        uint2 brT[4]; float sT0, sT1;
        LOADB(brT, sT0, sT1, 0);
        LOADB(brB, sB0, sB1, 1);
        DECODE(brT, bdA, sT0, sT1);
    }
    asm volatile("s_waitcnt vmcnt(6)" ::: "memory");
    __builtin_amdgcn_sched_barrier(0);
    __builtin_amdgcn_s_barrier();
    asm volatile("" ::: "memory");

#pragma unroll 1
    for (int tb = 0; tb < NSTEP; tb += 4) {
        KSTEP(0, 0, 2, brA, sA0, sA1, brB, bdB, sB0, sB1, bdA);
        KSTEP(1, 1, 3, brB, sB0, sB1, brA, bdA, sA0, sA1, bdB);
        KSTEP(2, 2, 0, brA, sA0, sA1, brB, bdB, sB0, sB1, bdA);
        KSTEP(3, 3, 1, brB, sB0, sB1, brA, bdA, sA0, sA1, bdB);
    }

    // ---- epilogue: acc + bias -> y (32x32 C/D: col=lane&31, row=(r&3)+8*(r>>2)+4*lh) ----
    const float bv0 = bias[n_0];
    const float bv1 = bias[n_1];
#pragma unroll
    for (int i = 0; i < 4; ++i) {
        const int mbase = m0 + wr * 128 + i * 32 + 4 * lh;
#pragma unroll
        for (int r = 0; r < 16; ++r) {
            const int mrow = mbase + (r & 3) + 8 * (r >> 2);
            float* yp = y + (size_t)mrow * NOUT;
            yp[n_0] = acc[i][0][r] + bv0;
            yp[n_1] = acc[i][1][r] + bv1;
        }
    }

#undef ISSUEA
#undef LOADB
#undef DECODE
#undef COMPUTE
#undef KBAR
#undef KSTEP
}

extern "C" void kernel_launch(void* const* d_in, const int* in_sizes, int n_in,
                              void* d_out, int out_size, void* d_ws, size_t ws_size,
                              hipStream_t stream)
{
    const float*   xin  = (const float*)d_in[0];
    const int32_t* pw   = (const int32_t*)d_in[1];   // harness pushes int8 as int32
    const float*   scal = (const float*)d_in[2];
    const float*   bias = (const float*)d_in[3];
    float* y = (float*)d_out;

    uint8_t* wsA = (uint8_t*)d_ws;
    uint8_t* wsB = wsA + WSB_OFF;

    prepA<<<dim3((MTOK / 256) * 512), 256, 0, stream>>>(xin, wsA);
    prepB<<<dim3(43, 512), 128, 0, stream>>>(pw, wsB);
    qlin_gemm<<<dim3(NTM * NTN), 256, 0, stream>>>(wsA, wsB, scal, bias, y);
}

// Round 7
// 504.441 us; speedup vs baseline: 1.1633x; 1.1633x over previous
//
#include <hip/hip_runtime.h>
#include <hip/hip_bf16.h>
#include <stdint.h>

#define NOUT 11008
#define KIN  4096
#define MTOK 4096
#define PLD  5504            // int32 elements per k-row of pw
#define BM 256
#define BN 128
#define BK 32
#define NSTEP (KIN/BK)       // 128
#define NTN (NOUT/BN)        // 86
#define NTM (MTOK/BM)        // 16
#define ACHUNK 16384         // bytes per (mt,t) A chunk: 256 rows * 64B
#define BCHUNK 8192          // bytes per (nt,t) B bf16 LDS-image
#define WSA_BYTES ((size_t)NTM * NSTEP * ACHUNK)   // 32 MB
#define WSW_BYTES ((size_t)NTN * NSTEP * BCHUNK)   // 90 MB
#define WSB_OFF   WSA_BYTES
#define WS_NEED_NEW (WSA_BYTES + WSW_BYTES)        // ~124 MB

typedef short bf16x8 __attribute__((ext_vector_type(8)));
typedef float f32x4  __attribute__((ext_vector_type(4)));

typedef __attribute__((address_space(3))) uint8_t lds_u8_t;
typedef __attribute__((address_space(1))) const uint8_t glb_u8_t;

__device__ __forceinline__ uint32_t bfpack(float lo, float hi){
    __hip_bfloat16 a = __float2bfloat16(lo);
    __hip_bfloat16 b = __float2bfloat16(hi);
    uint16_t ua, ub;
    __builtin_memcpy(&ua, &a, 2);
    __builtin_memcpy(&ub, &b, 2);
    return (uint32_t)ua | ((uint32_t)ub << 16);
}

// A-LDS swizzle: rows are 64B (32k * 2B)
__device__ __forceinline__ int swzA(int m){ return ((m >> 1) & 3) << 4; }

// ---------------- pre-pass A (shared): x fp32 -> bf16, tiled+swizzled into wsA ----------------
__global__ __launch_bounds__(256)
void prepA(const float* __restrict__ x, uint8_t* __restrict__ wsA)
{
    int gid = blockIdx.x * 256 + threadIdx.x;      // 4096 * 1024
    int m  = gid >> 10;
    int k  = (gid & 1023) << 2;
    float4 v = *reinterpret_cast<const float4*>(x + (size_t)m * KIN + k);
    uint32_t lo = bfpack(v.x, v.y), hi = bfpack(v.z, v.w);
    int mt = m >> 8, ml = m & 255, t = k >> 5, kl = k & 31;
    size_t dst = (size_t)(mt * NSTEP + t) * ACHUNK + ml * 64 + ((kl * 2) ^ swzA(ml));
    *reinterpret_cast<uint2*>(wsA + dst) = make_uint2(lo, hi);
}

// ---------------- pre-pass W (NEW path): dequant int4 -> bf16 LDS-images in wsW ----------------
// One block per (t, nt); thread role (npw = tid&63, koct = tid>>6) mirrors v5's decodeWrite.
__global__ __launch_bounds__(256)
void prepW(const int32_t* __restrict__ pw, const float* __restrict__ sc,
           uint8_t* __restrict__ wsW)
{
    const int t  = blockIdx.x;                     // 0..127  (k-step)
    const int nt = blockIdx.y;                     // 0..85
    const int tid  = threadIdx.x;
    const int npw  = tid & 63;
    const int koct = tid >> 6;                     // 0..3

    const int kbase = t * BK + koct * 8;
    const int np    = nt * 64 + npw;               // global column-pair
    const int32_t* p = pw + (size_t)kbase * PLD + np;
    uint32_t b[8];
#pragma unroll
    for (int i = 0; i < 8; ++i) b[i] = (uint32_t)p[(size_t)i * PLD] & 0xFFu;

    const int kb = t >> 2;                         // scale block
    const float s0 = sc[(size_t)kb * NOUT + 2 * np];
    const float s1 = sc[(size_t)kb * NOUT + 2 * np + 1];
    const float a0 = -8.f * s0, a1 = -8.f * s1;
    float fe[8], fo[8];
#pragma unroll
    for (int i = 0; i < 8; ++i) {
        fe[i] = fmaf((float)(b[i] & 15u), s0, a0);
        fo[i] = fmaf((float)(b[i] >> 4),  s1, a1);
    }

    const int sww = (npw >> 3) & 1;
    uint8_t* out = wsW + (size_t)(nt * NSTEP + t) * BCHUNK;
    int wOff[2][2];
#pragma unroll
    for (int kq = 0; kq < 2; ++kq)
#pragma unroll
        for (int pp = 0; pp < 2; ++pp)
            wOff[kq][pp] = npw * 128 + ((((koct * 2 + kq) ^ (npw & 7)) << 4)) + (((pp ^ sww) << 3));

    uint2 g;
    g.x = bfpack(fe[0], fe[1]); g.y = bfpack(fe[2], fe[3]);
    *reinterpret_cast<uint2*>(out + wOff[0][0]) = g;
    g.x = bfpack(fe[4], fe[5]); g.y = bfpack(fe[6], fe[7]);
    *reinterpret_cast<uint2*>(out + wOff[1][0]) = g;
    g.x = bfpack(fo[0], fo[1]); g.y = bfpack(fo[2], fo[3]);
    *reinterpret_cast<uint2*>(out + wOff[0][1]) = g;
    g.x = bfpack(fo[4], fo[5]); g.y = bfpack(fo[6], fo[7]);
    *reinterpret_cast<uint2*>(out + wOff[1][1]) = g;
}

// ---------------- NEW main GEMM: pure bf16, A+B both global_load_lds ----------------
__global__ __launch_bounds__(256, 2)
void qlin_gemm_pre(const uint8_t* __restrict__ wsA, const uint8_t* __restrict__ wsW,
                   const float* __restrict__ bias, float* __restrict__ y)
{
    __shared__ __align__(16) uint8_t ldsA[3][ACHUNK];   // 48 KB
    __shared__ __align__(16) uint8_t ldsB[3][BCHUNK];   // 24 KB

    const int tid  = threadIdx.x;
    const int lane = tid & 63;
    const int wid  = tid >> 6;
    const int wr = wid >> 1, wc = wid & 1;   // wave tile 128x64

    const int lb = (blockIdx.x & 7) * 172 + (blockIdx.x >> 3);  // bijective XCD swizzle
    const int mt = lb / NTN, nt = lb % NTN;
    const int m0 = mt * BM, n0 = nt * BN;

    const int cl = lane & 15;
    const int k8 = lane >> 4;

    int aOff[8];
#pragma unroll
    for (int i = 0; i < 8; ++i) {
        int ml = wr * 128 + i * 16 + cl;
        aOff[i] = ml * 64 + ((k8 * 16) ^ swzA(ml));
    }
    int bOff[4][2];
#pragma unroll
    for (int j = 0; j < 4; ++j) {
        int n = wc * 64 + j * 16 + cl;
        int npr = n >> 1, p = n & 1;
#pragma unroll
        for (int h = 0; h < 2; ++h) {
            int q8 = k8 * 2 + h;
            bOff[j][h] = npr * 128 + (((q8 ^ (npr & 7)) << 4)) + (((p ^ ((npr >> 3) & 1)) << 3));
        }
    }

    const uint8_t* wsAbase = wsA + (size_t)mt * NSTEP * ACHUNK;
    const uint8_t* wsWbase = wsW + (size_t)nt * NSTEP * BCHUNK;

    f32x4 acc[8][4];
#pragma unroll
    for (int i = 0; i < 8; ++i)
#pragma unroll
        for (int j = 0; j < 4; ++j)
            acc[i][j] = (f32x4){0.f, 0.f, 0.f, 0.f};

    auto issueA = [&](int t, int buf) {
        const uint8_t* g = wsAbase + (size_t)t * ACHUNK + tid * 16;
        lds_u8_t* l = (lds_u8_t*)(&ldsA[buf][tid * 16]);
#pragma unroll
        for (int q = 0; q < 4; ++q)
            __builtin_amdgcn_global_load_lds((glb_u8_t*)(g + q * 4096), l + q * 4096, 16, 0, 0);
    };
    auto issueB = [&](int t, int buf) {
        const uint8_t* g = wsWbase + (size_t)t * BCHUNK + tid * 16;
        lds_u8_t* l = (lds_u8_t*)(&ldsB[buf][tid * 16]);
        __builtin_amdgcn_global_load_lds((glb_u8_t*)(g),        l,        16, 0, 0);
        __builtin_amdgcn_global_load_lds((glb_u8_t*)(g + 4096), l + 4096, 16, 0, 0);
    };
    auto compute = [&](int buf) {
        const uint8_t* La = ldsA[buf];
        const uint8_t* Lb = ldsB[buf];
        bf16x8 af[8], bfr[4];
#pragma unroll
        for (int i = 0; i < 8; ++i)
            af[i] = *reinterpret_cast<const bf16x8*>(La + aOff[i]);
#pragma unroll
        for (int j = 0; j < 4; ++j) {
            uint64_t v[2];
            v[0] = *reinterpret_cast<const uint64_t*>(Lb + bOff[j][0]);
            v[1] = *reinterpret_cast<const uint64_t*>(Lb + bOff[j][1]);
            __builtin_memcpy(&bfr[j], v, 16);
        }
        __builtin_amdgcn_s_setprio(1);
#pragma unroll
        for (int i = 0; i < 8; ++i)
#pragma unroll
            for (int j = 0; j < 4; ++j)
                acc[i][j] = __builtin_amdgcn_mfma_f32_16x16x32_bf16(af[i], bfr[j], acc[i][j], 0, 0, 0);
        __builtin_amdgcn_s_setprio(0);
    };

    // prologue: tiles 0,1 in flight (6 vmem each)
    issueA(0, 0); issueB(0, 0);
    issueA(1, 1); issueB(1, 1);
    asm volatile("s_waitcnt vmcnt(6)" ::: "memory");
    __builtin_amdgcn_sched_barrier(0);
    __builtin_amdgcn_s_barrier();
    asm volatile("" ::: "memory");

    int bc = 0, bi = 2;
#pragma unroll 1
    for (int t = 0; t < NSTEP; ++t) {
        const int tp = (t + 2 < NSTEP) ? (t + 2) : (NSTEP - 1);  // uniform: 6 vmem/step
        issueA(tp, bi);
        issueB(tp, bi);
        compute(bc);
        asm volatile("s_waitcnt vmcnt(6)" ::: "memory");
        __builtin_amdgcn_sched_barrier(0);
        __builtin_amdgcn_s_barrier();
        asm volatile("" ::: "memory");
        bc = (bc == 2) ? 0 : bc + 1;
        bi = (bi == 2) ? 0 : bi + 1;
    }

    // epilogue
    float bv[4];
#pragma unroll
    for (int j = 0; j < 4; ++j) bv[j] = bias[n0 + wc * 64 + j * 16 + cl];
    const int rg = (lane >> 4) * 4;
#pragma unroll
    for (int i = 0; i < 8; ++i) {
        const int mrow = m0 + wr * 128 + i * 16 + rg;
#pragma unroll
        for (int r = 0; r < 4; ++r) {
            float* yp = y + (size_t)(mrow + r) * NOUT + n0 + wc * 64 + cl;
#pragma unroll
            for (int j = 0; j < 4; ++j)
                yp[j * 16] = acc[i][j][r] + bv[j];
        }
    }
}

// =================== FALLBACK PATH: exact round-5 kernels ===================
__global__ __launch_bounds__(128)
void prepB(const int32_t* __restrict__ pw, uint8_t* __restrict__ wsB)
{
    int np   = blockIdx.x * 128 + threadIdx.x;
    int koct = blockIdx.y;
    const int32_t* p = pw + (size_t)koct * 8 * PLD + np;
    uint32_t b[8];
#pragma unroll
    for (int i = 0; i < 8; ++i) b[i] = (uint32_t)p[(size_t)i * PLD] & 0xFFu;
    uint32_t lo = b[0] | (b[1] << 8) | (b[2] << 16) | (b[3] << 24);
    uint32_t hi = b[4] | (b[5] << 8) | (b[6] << 16) | (b[7] << 24);
    *reinterpret_cast<uint2*>(wsB + ((size_t)koct * PLD + np) * 8) = make_uint2(lo, hi);
}

__global__ __launch_bounds__(256, 2)
void qlin_gemm_v5(const uint8_t* __restrict__ wsA, const uint8_t* __restrict__ wsB,
                  const float* __restrict__ sc, const float* __restrict__ bias,
                  float* __restrict__ y)
{
    __shared__ __align__(16) uint8_t ldsA[3][BM * 64];
    __shared__ __align__(16) uint8_t ldsB[3][64 * 128];

    const int tid  = threadIdx.x;
    const int lane = tid & 63;
    const int wid  = tid >> 6;
    const int wr = wid >> 1, wc = wid & 1;

    const int lb = (blockIdx.x & 7) * 172 + (blockIdx.x >> 3);
    const int mt = lb / NTN, nt = lb % NTN;
    const int m0 = mt * BM, n0 = nt * BN;

    const int cl = lane & 15;
    const int k8 = lane >> 4;

    int aOff[8];
#pragma unroll
    for (int i = 0; i < 8; ++i) {
        int ml = wr * 128 + i * 16 + cl;
        aOff[i] = ml * 64 + ((k8 * 16) ^ swzA(ml));
    }
    int bOff[4][2];
#pragma unroll
    for (int j = 0; j < 4; ++j) {
        int n = wc * 64 + j * 16 + cl;
        int npr = n >> 1, p = n & 1;
#pragma unroll
        for (int h = 0; h < 2; ++h) {
            int q8 = k8 * 2 + h;
            bOff[j][h] = npr * 128 + (((q8 ^ (npr & 7)) << 4)) + (((p ^ ((npr >> 3) & 1)) << 3));
        }
    }
    const int npw  = tid & 63;
    const int koct = wid;
    const int sww  = (npw >> 3) & 1;
    int wOff[2][2];
#pragma unroll
    for (int kq = 0; kq < 2; ++kq)
#pragma unroll
        for (int p = 0; p < 2; ++p)
            wOff[kq][p] = npw * 128 + ((((koct * 2 + kq) ^ (npw & 7)) << 4)) + (((p ^ sww) << 3));

    const size_t npg = (size_t)(n0 >> 1) + npw;
    const uint8_t* wsAbase = wsA + (size_t)mt * NSTEP * ACHUNK;
    const float* scb = sc + n0 + 2 * npw;

    f32x4 acc[8][4];
#pragma unroll
    for (int i = 0; i < 8; ++i)
#pragma unroll
        for (int j = 0; j < 4; ++j)
            acc[i][j] = (f32x4){0.f, 0.f, 0.f, 0.f};

    auto issueA = [&](int t, int buf) {
        const uint8_t* g = wsAbase + (size_t)t * ACHUNK + tid * 16;
        lds_u8_t* l = (lds_u8_t*)(&ldsA[buf][tid * 16]);
#pragma unroll
        for (int q = 0; q < 4; ++q)
            __builtin_amdgcn_global_load_lds((glb_u8_t*)(g + q * 4096), l + q * 4096, 16, 0, 0);
    };
    auto loadB = [&](int t) {
        return *reinterpret_cast<const uint2*>(wsB + ((size_t)(t * 4 + koct) * PLD + npg) * 8);
    };
    auto loadS = [&](int t) {
        return *reinterpret_cast<const float2*>(scb + (size_t)(t >> 2) * NOUT);
    };
    auto decodeWrite = [&](uint2 braw, float2 s, int buf) {
        uint8_t* Lb = ldsB[buf];
        const float a0 = -8.f * s.x, a1 = -8.f * s.y;
        uint32_t l0 = braw.x & 0x0f0f0f0fu, h0 = (braw.x >> 4) & 0x0f0f0f0fu;
        uint32_t l1 = braw.y & 0x0f0f0f0fu, h1 = (braw.y >> 4) & 0x0f0f0f0fu;
        float fe[8], fo[8];
#pragma unroll
        for (int i = 0; i < 4; ++i) {
            fe[i]     = fmaf((float)((l0 >> (8 * i)) & 0xFFu), s.x, a0);
            fe[i + 4] = fmaf((float)((l1 >> (8 * i)) & 0xFFu), s.x, a0);
            fo[i]     = fmaf((float)((h0 >> (8 * i)) & 0xFFu), s.y, a1);
            fo[i + 4] = fmaf((float)((h1 >> (8 * i)) & 0xFFu), s.y, a1);
        }
        uint2 g;
        g.x = bfpack(fe[0], fe[1]); g.y = bfpack(fe[2], fe[3]);
        *reinterpret_cast<uint2*>(Lb + wOff[0][0]) = g;
        g.x = bfpack(fe[4], fe[5]); g.y = bfpack(fe[6], fe[7]);
        *reinterpret_cast<uint2*>(Lb + wOff[1][0]) = g;
        g.x = bfpack(fo[0], fo[1]); g.y = bfpack(fo[2], fo[3]);
        *reinterpret_cast<uint2*>(Lb + wOff[0][1]) = g;
        g.x = bfpack(fo[4], fo[5]); g.y = bfpack(fo[6], fo[7]);
        *reinterpret_cast<uint2*>(Lb + wOff[1][1]) = g;
    };
    auto compute = [&](int buf) {
        const uint8_t* La = ldsA[buf];
        const uint8_t* Lb = ldsB[buf];
        bf16x8 af[8], bfr[4];
#pragma unroll
        for (int i = 0; i < 8; ++i)
            af[i] = *reinterpret_cast<const bf16x8*>(La + aOff[i]);
#pragma unroll
        for (int j = 0; j < 4; ++j) {
            uint64_t v[2];
            v[0] = *reinterpret_cast<const uint64_t*>(Lb + bOff[j][0]);
            v[1] = *reinterpret_cast<const uint64_t*>(Lb + bOff[j][1]);
            __builtin_memcpy(&bfr[j], v, 16);
        }
        __builtin_amdgcn_s_setprio(1);
#pragma unroll
        for (int i = 0; i < 8; ++i)
#pragma unroll
            for (int j = 0; j < 4; ++j)
                acc[i][j] = __builtin_amdgcn_mfma_f32_16x16x32_bf16(af[i], bfr[j], acc[i][j], 0, 0, 0);
        __builtin_amdgcn_s_setprio(0);
    };

    issueA(0, 0);
    asm volatile("" ::: "memory");
    uint2  braw_cur = loadB(0);
    float2 sfl_cur  = loadS(0);
    asm volatile("" ::: "memory");
    issueA(1, 1);
    asm volatile("" ::: "memory");
    uint2  braw_nxt = loadB(1);
    float2 sfl_nxt  = loadS(1);
    asm volatile("" ::: "memory");
    decodeWrite(braw_cur, sfl_cur, 0);
    asm volatile("s_waitcnt vmcnt(6) lgkmcnt(0)" ::: "memory");
    __builtin_amdgcn_sched_barrier(0);
    __builtin_amdgcn_s_barrier();
    asm volatile("" ::: "memory");

    int bc = 0, bw = 1, bi = 2;
#pragma unroll 1
    for (int t = 0; t < NSTEP; ++t) {
        const int tp = (t + 2 < NSTEP) ? (t + 2) : (NSTEP - 1);
        issueA(tp, bi);
        asm volatile("" ::: "memory");
        uint2  braw2 = loadB(tp);
        float2 sfl2  = loadS(tp);
        decodeWrite(braw_nxt, sfl_nxt, bw);
        compute(bc);
        braw_nxt = braw2; sfl_nxt = sfl2;
        asm volatile("s_waitcnt vmcnt(6) lgkmcnt(0)" ::: "memory");
        __builtin_amdgcn_sched_barrier(0);
        __builtin_amdgcn_s_barrier();
        asm volatile("" ::: "memory");
        int nb = bc; bc = bw; bw = bi; bi = nb;
    }

    float bv[4];
#pragma unroll
    for (int j = 0; j < 4; ++j) bv[j] = bias[n0 + wc * 64 + j * 16 + cl];
    const int rg = (lane >> 4) * 4;
#pragma unroll
    for (int i = 0; i < 8; ++i) {
        const int mrow = m0 + wr * 128 + i * 16 + rg;
#pragma unroll
        for (int r = 0; r < 4; ++r) {
            float* yp = y + (size_t)(mrow + r) * NOUT + n0 + wc * 64 + cl;
#pragma unroll
            for (int j = 0; j < 4; ++j)
                yp[j * 16] = acc[i][j][r] + bv[j];
        }
    }
}

extern "C" void kernel_launch(void* const* d_in, const int* in_sizes, int n_in,
                              void* d_out, int out_size, void* d_ws, size_t ws_size,
                              hipStream_t stream)
{
    const float*   xin  = (const float*)d_in[0];
    const int32_t* pw   = (const int32_t*)d_in[1];   // harness pushes int8 as int32
    const float*   scal = (const float*)d_in[2];
    const float*   bias = (const float*)d_in[3];
    float* y = (float*)d_out;

    uint8_t* wsA = (uint8_t*)d_ws;

    prepA<<<dim3((MTOK * (KIN / 4)) / 256), 256, 0, stream>>>(xin, wsA);

    if (ws_size >= WS_NEED_NEW) {
        uint8_t* wsW = wsA + WSA_BYTES;
        prepW<<<dim3(NSTEP, NTN), 256, 0, stream>>>(pw, scal, wsW);
        qlin_gemm_pre<<<dim3(NTM * NTN), 256, 0, stream>>>(wsA, wsW, bias, y);
    } else {
        uint8_t* wsB = wsA + WSB_OFF;
        prepB<<<dim3(43, 512), 128, 0, stream>>>(pw, wsB);
        qlin_gemm_v5<<<dim3(NTM * NTN), 256, 0, stream>>>(wsA, wsB, scal, bias, y);
    }
}

// Round 8
// 411.176 us; speedup vs baseline: 1.4272x; 1.2268x over previous
//
#include <hip/hip_runtime.h>
#include <hip/hip_bf16.h>
#include <stdint.h>

#define NOUT 11008
#define KIN  4096
#define MTOK 4096
#define PLD  5504            // int32 elements per k-row of pw
#define NSTEP 128            // K-tiles of 32
#define NTN 43               // 11008 / 256
#define NTM 16               // 4096 / 256
#define ACHUNK 16384         // 256 rows x 32k x 2B
#define BCHUNK 16384         // 256 cols x 32k x 2B
#define WSA_BYTES ((size_t)NTM * NSTEP * ACHUNK)   // 32 MB
#define WSW_BYTES ((size_t)NTN * NSTEP * BCHUNK)   // 90.2 MB (ws >= 124 MB confirmed r7)

typedef short bf16x8 __attribute__((ext_vector_type(8)));
typedef float f32x4  __attribute__((ext_vector_type(4)));

typedef __attribute__((address_space(3))) uint8_t lds_u8_t;
typedef __attribute__((address_space(1))) const uint8_t glb_u8_t;

__device__ __forceinline__ uint32_t bfpack(float lo, float hi){
    __hip_bfloat16 a = __float2bfloat16(lo);
    __hip_bfloat16 b = __float2bfloat16(hi);
    uint16_t ua, ub;
    __builtin_memcpy(&ua, &a, 2);
    __builtin_memcpy(&ub, &b, 2);
    return (uint32_t)ua | ((uint32_t)ub << 16);
}

// row/col-local slot swizzle (proven rounds 3-7): 4 x 16B slots XORed by ((r>>1)&3)
__device__ __forceinline__ int swzA(int r){ return ((r >> 1) & 3) << 4; }

// ---------------- pre-pass A: x fp32 -> bf16, [mt][t][m 0..255][64B k-stripe swz] ----------------
__global__ __launch_bounds__(256)
void prepA(const float* __restrict__ x, uint8_t* __restrict__ wsA)
{
    int gid = blockIdx.x * 256 + threadIdx.x;      // 4096 rows * 1024 k-quads
    int m  = gid >> 10;
    int k  = (gid & 1023) << 2;
    float4 v = *reinterpret_cast<const float4*>(x + (size_t)m * KIN + k);
    uint32_t lo = bfpack(v.x, v.y), hi = bfpack(v.z, v.w);
    int mt = m >> 8, ml = m & 255, t = k >> 5, kl = k & 31;
    size_t dst = (size_t)(mt * NSTEP + t) * ACHUNK + ml * 64 + ((kl * 2) ^ swzA(ml));
    *reinterpret_cast<uint2*>(wsA + dst) = make_uint2(lo, hi);
}

// ---------------- pre-pass W: dequant int4 -> bf16 chunks [nt][t][col 0..255][64B swz] ----------------
__global__ __launch_bounds__(256)
void prepW2(const int32_t* __restrict__ pw, const float* __restrict__ sc,
            uint8_t* __restrict__ wsW)
{
    const int t  = blockIdx.x;                 // 0..127 (k-tile of 32)
    const int nt = blockIdx.y;                 // 0..42
    const int c  = threadIdx.x;                // col within 256
    const int col = nt * 256 + c;
    const int np  = col >> 1;
    const uint32_t sh = (uint32_t)(col & 1) * 4;
    const int32_t* p = pw + (size_t)(t * 32) * PLD + np;
    const float s  = sc[(size_t)(t >> 2) * NOUT + col];
    const float m8 = -8.f * s;
    uint8_t* out = wsW + ((size_t)nt * NSTEP + t) * BCHUNK + c * 64;
#pragma unroll
    for (int k8 = 0; k8 < 4; ++k8) {
        uint32_t r[4];
#pragma unroll
        for (int kk = 0; kk < 4; ++kk) {
            uint32_t w0 = (uint32_t)p[(size_t)(k8 * 8 + kk * 2)     * PLD];
            uint32_t w1 = (uint32_t)p[(size_t)(k8 * 8 + kk * 2 + 1) * PLD];
            float f0 = fmaf((float)((w0 >> sh) & 15u), s, m8);
            float f1 = fmaf((float)((w1 >> sh) & 15u), s, m8);
            r[kk] = bfpack(f0, f1);
        }
        *reinterpret_cast<uint4*>(out + ((k8 * 16) ^ swzA(c))) = *reinterpret_cast<uint4*>(r);
    }
}

// ---------------- main GEMM: 256x256 tile, 8 waves, 8-phase counted-vmcnt pipeline ----------------
__global__ __launch_bounds__(512, 1)
void qlin_gemm8(const uint8_t* __restrict__ wsA, const uint8_t* __restrict__ wsW,
                const float* __restrict__ bias, float* __restrict__ y)
{
    __shared__ __align__(16) uint8_t ldsA[4][ACHUNK];   // 64 KB
    __shared__ __align__(16) uint8_t ldsB[4][BCHUNK];   // 64 KB

    const int tid  = threadIdx.x;
    const int lane = tid & 63;
    const int wid  = tid >> 6;            // 0..7
    const int wr = wid >> 2, wc = wid & 3;   // 2x4 wave grid, 128x64 per wave

    // bijective XCD swizzle: 688 = 8 * 86
    const int lb = (blockIdx.x & 7) * 86 + (blockIdx.x >> 3);
    const int mt = lb / NTN, nt = lb % NTN;
    const int m0 = mt * 256, n0 = nt * 256;

    const int cl = lane & 15;
    const int k8 = lane >> 4;

    int aOff[8];
#pragma unroll
    for (int i = 0; i < 8; ++i) {
        int ml = wr * 128 + i * 16 + cl;
        aOff[i] = ml * 64 + ((k8 * 16) ^ swzA(ml));
    }
    int bOff[4];
#pragma unroll
    for (int j = 0; j < 4; ++j) {
        int cc = wc * 64 + j * 16 + cl;
        bOff[j] = cc * 64 + ((k8 * 16) ^ swzA(cc));
    }

    const uint8_t* wsAbase = wsA + (size_t)mt * NSTEP * ACHUNK;
    const uint8_t* wsWbase = wsW + (size_t)nt * NSTEP * BCHUNK;

    f32x4 acc[8][4];
#pragma unroll
    for (int i = 0; i < 8; ++i)
#pragma unroll
        for (int j = 0; j < 4; ++j)
            acc[i][j] = (f32x4){0.f, 0.f, 0.f, 0.f};

    bf16x8 af[4], bfr[4];

#define STAGE_A(buf, t) do { \
    const uint8_t* g_ = wsAbase + (size_t)(t) * ACHUNK + tid * 16; \
    __builtin_amdgcn_global_load_lds((glb_u8_t*)(g_),        (lds_u8_t*)(&ldsA[buf][tid*16]),        16, 0, 0); \
    __builtin_amdgcn_global_load_lds((glb_u8_t*)(g_ + 8192), (lds_u8_t*)(&ldsA[buf][tid*16 + 8192]), 16, 0, 0); \
} while(0)

#define STAGE_B(buf, t) do { \
    const uint8_t* g_ = wsWbase + (size_t)(t) * BCHUNK + tid * 16; \
    __builtin_amdgcn_global_load_lds((glb_u8_t*)(g_),        (lds_u8_t*)(&ldsB[buf][tid*16]),        16, 0, 0); \
    __builtin_amdgcn_global_load_lds((glb_u8_t*)(g_ + 8192), (lds_u8_t*)(&ldsB[buf][tid*16 + 8192]), 16, 0, 0); \
} while(0)

#define BAR() do { \
    asm volatile("" ::: "memory"); \
    __builtin_amdgcn_s_barrier(); \
    asm volatile("" ::: "memory"); \
} while(0)

    // odd phase: compute (buf cb, m-half 0), stage A chunk; reads B-frags (held for even phase)
#define PHASE_ODD(cb, sb, st) do { \
    STAGE_A(sb, st); \
    _Pragma("unroll") \
    for (int i = 0; i < 4; ++i) \
        af[i] = *reinterpret_cast<const bf16x8*>(ldsA[cb] + aOff[i]); \
    _Pragma("unroll") \
    for (int j = 0; j < 4; ++j) \
        bfr[j] = *reinterpret_cast<const bf16x8*>(ldsB[cb] + bOff[j]); \
    BAR(); \
    asm volatile("s_waitcnt lgkmcnt(0)" ::: "memory"); \
    __builtin_amdgcn_sched_barrier(0); \
    __builtin_amdgcn_s_setprio(1); \
    _Pragma("unroll") \
    for (int j = 0; j < 4; ++j) \
        _Pragma("unroll") \
        for (int i = 0; i < 4; ++i) \
            acc[i][j] = __builtin_amdgcn_mfma_f32_16x16x32_bf16(af[i], bfr[j], acc[i][j], 0, 0, 0); \
    __builtin_amdgcn_s_setprio(0); \
    BAR(); \
} while(0)

    // even phase: compute (buf cb, m-half 1) reusing bfr, stage B chunk, counted vmcnt
#define PHASE_EVEN(cb, sb, st) do { \
    STAGE_B(sb, st); \
    _Pragma("unroll") \
    for (int i = 0; i < 4; ++i) \
        af[i] = *reinterpret_cast<const bf16x8*>(ldsA[cb] + aOff[4 + i]); \
    BAR(); \
    asm volatile("s_waitcnt lgkmcnt(0)" ::: "memory"); \
    __builtin_amdgcn_sched_barrier(0); \
    __builtin_amdgcn_s_setprio(1); \
    _Pragma("unroll") \
    for (int j = 0; j < 4; ++j) \
        _Pragma("unroll") \
        for (int i = 0; i < 4; ++i) \
            acc[4 + i][j] = __builtin_amdgcn_mfma_f32_16x16x32_bf16(af[i], bfr[j], acc[4 + i][j], 0, 0, 0); \
    __builtin_amdgcn_s_setprio(0); \
    asm volatile("s_waitcnt vmcnt(8)" ::: "memory"); \
    __builtin_amdgcn_sched_barrier(0); \
    BAR(); \
} while(0)

    // ---- prologue: stage tiles 0,1,2 into bufs 0,1,2 (tile 3 staged in iter-0 ph1/ph2) ----
    STAGE_A(0, 0); STAGE_B(0, 0);
    STAGE_A(1, 1); STAGE_B(1, 1);
    STAGE_A(2, 2); STAGE_B(2, 2);
    asm volatile("s_waitcnt vmcnt(8)" ::: "memory");   // tile 0 (oldest 4 loads) landed
    __builtin_amdgcn_sched_barrier(0);
    BAR();

    // ---- main loop: 32 iterations x 4 K-tiles, 8 phases each ----
#pragma unroll 1
    for (int tb = 0; tb < NSTEP; tb += 4) {
        const int s4 = (tb + 4 < NSTEP) ? tb + 4 : NSTEP - 1;
        const int s5 = (tb + 5 < NSTEP) ? tb + 5 : NSTEP - 1;
        const int s6 = (tb + 6 < NSTEP) ? tb + 6 : NSTEP - 1;
        PHASE_ODD (0, 3, tb + 3);   // ph1: tile tb+0 mh0 | stage A3 <- tb+3
        PHASE_EVEN(0, 3, tb + 3);   // ph2: tile tb+0 mh1 | stage B3 <- tb+3 | vmcnt(8)
        PHASE_ODD (1, 0, s4);       // ph3: tile tb+1 mh0 | stage A0 <- tb+4
        PHASE_EVEN(1, 0, s4);       // ph4
        PHASE_ODD (2, 1, s5);       // ph5: tile tb+2
        PHASE_EVEN(2, 1, s5);       // ph6
        PHASE_ODD (3, 2, s6);       // ph7: tile tb+3
        PHASE_EVEN(3, 2, s6);       // ph8
    }

    // ---- epilogue: acc + bias -> y (C/D: col=lane&15, row=(lane>>4)*4+reg) ----
    float bv[4];
#pragma unroll
    for (int j = 0; j < 4; ++j) bv[j] = bias[n0 + wc * 64 + j * 16 + cl];
    const int rg = (lane >> 4) * 4;
#pragma unroll
    for (int i = 0; i < 8; ++i) {
        const int mrow = m0 + wr * 128 + i * 16 + rg;
#pragma unroll
        for (int r = 0; r < 4; ++r) {
            float* yp = y + (size_t)(mrow + r) * NOUT + n0 + wc * 64 + cl;
#pragma unroll
            for (int j = 0; j < 4; ++j)
                yp[j * 16] = acc[i][j][r] + bv[j];
        }
    }

#undef STAGE_A
#undef STAGE_B
#undef BAR
#undef PHASE_ODD
#undef PHASE_EVEN
}

extern "C" void kernel_launch(void* const* d_in, const int* in_sizes, int n_in,
                              void* d_out, int out_size, void* d_ws, size_t ws_size,
                              hipStream_t stream)
{
    const float*   xin  = (const float*)d_in[0];
    const int32_t* pw   = (const int32_t*)d_in[1];   // harness pushes int8 as int32
    const float*   scal = (const float*)d_in[2];
    const float*   bias = (const float*)d_in[3];
    float* y = (float*)d_out;

    uint8_t* wsA = (uint8_t*)d_ws;
    uint8_t* wsW = wsA + WSA_BYTES;     // needs 122 MB total; ws >= 124 MB (proven round 7)

    prepA<<<dim3((MTOK * (KIN / 4)) / 256), 256, 0, stream>>>(xin, wsA);
    prepW2<<<dim3(NSTEP, NTN), 256, 0, stream>>>(pw, scal, wsW);
    qlin_gemm8<<<dim3(NTM * NTN), 512, 0, stream>>>(wsA, wsW, bias, y);
}